// Round 1
// baseline (2229.255 us; speedup 1.0000x reference)
//
#include <hip/hip_runtime.h>
#include <stdint.h>

// Resonator network, b=1024 f=4 v=64 d=2048, 100 iterations.
// All values are +-1 -> pure bit arithmetic (exact vs f32 reference).

#define NB 1024
#define NF 4
#define NV 64
#define ND 2048
#define NW 32            // ND/64 words per row
#define ITERS 100

#define OFF_OUT  (NB*NF*ND)            // 8388608  (outcome)
#define OFF_MS   (OFF_OUT + NB*NF)     // 8392704  (max_sims[-1])
#define OFF_CONV (OFF_MS + NB*NF)      // 8396800  (convergence scalar)

typedef unsigned long long u64;

// Pack codebooks (f,v,d) +-1 floats into two bit layouts in d_ws:
//  cbB[(j*32+w)*64 + v] : row bits, bit l = sign of cb[j,v,w*64+l]
//  cbT[j*2048 + d]      : column mask, bit v = sign of cb[j,v,d]
__global__ void pack_cb_kernel(const float* __restrict__ cb,
                               u64* __restrict__ cbB, u64* __restrict__ cbT) {
    const int lane = threadIdx.x & 63;
    const int gw   = (blockIdx.x * (blockDim.x >> 6)) + (threadIdx.x >> 6);
    const int nw   = (gridDim.x * blockDim.x) >> 6;
    for (int idx = gw; idx < NF * NV * NW; idx += nw) {
        const int j = idx >> 11, v = (idx >> 5) & 63, w = idx & 31;
        const float x = cb[(((j << 6) | v) << 11) + (w << 6) + lane];
        const u64 m = __ballot(x < 0.0f);
        if (lane == 0) cbB[(((j << 5) | w) << 6) | v] = m;
    }
    for (int idx = gw; idx < NF * ND; idx += nw) {
        const int j = idx >> 11, d = idx & 2047;
        const float x = cb[(((j << 6) | lane) << 11) + d];
        const u64 m = __ballot(x < 0.0f);
        if (lane == 0) cbT[idx] = m;
    }
}

// One block per batch row b. wave (tid>>6) = factor j. lane = v (phase B) or
// d%64 (phase C). Entire 100-iteration loop in-kernel; early exit on exact
// period-1 / period-2 orbits (provably identical result to full 100 steps).
__global__ __launch_bounds__(256, 4) void resonator_kernel(
    const float* __restrict__ inp, const float* __restrict__ est_init,
    const u64* __restrict__ cbB, const u64* __restrict__ cbT,
    float* __restrict__ out) {
    __shared__ u64 s_est[3][NF][NW];   // rotating state history S_{it-1},S_it,S_{it+1}
    __shared__ u64 s_inp[NW];
    __shared__ u64 s_X[NW];            // inp ^ est0 ^ est1 ^ est2 ^ est3
    __shared__ int s_conv[NF];

    const int b    = blockIdx.x;
    const int tid  = threadIdx.x;
    const int j    = tid >> 6;
    const int lane = tid & 63;

    // ---- pack this row's input and init estimates (ballot over sign) ----
    #pragma unroll
    for (int k = 0; k < 8; ++k) {
        const int w = (j << 3) + k;
        const float x = inp[(b << 11) + (w << 6) + lane];
        const u64 m = __ballot(x < 0.0f);
        if (lane == 0) s_inp[w] = m;
    }
    #pragma unroll 4
    for (int k = 0; k < NW; ++k) {
        const float x = est_init[(((b << 2) | j) << 11) + (k << 6) + lane];
        const u64 m = __ballot(x < 0.0f);
        if (lane == 0) s_est[0][j][k] = m;
    }
    __syncthreads();

    const u64* cbBj = cbB + (j << 11);   // row bits for factor j
    const u64* cbTj = cbT + (j << 11);   // column masks for factor j

    int   final_slot = 0;
    float m_last = 0.0f;
    int   m_prev = 0;

    for (int it = 0; it < ITERS; ++it) {
        const int cur = it % 3;
        const int nxt = (cur + 1 == 3) ? 0 : cur + 1;
        const int pv2 = (nxt + 1 == 3) ? 0 : nxt + 1;   // (it-1) % 3

        if (tid < NW) {
            s_X[tid] = s_inp[tid] ^ s_est[cur][0][tid] ^ s_est[cur][1][tid]
                                  ^ s_est[cur][2][tid] ^ s_est[cur][3][tid];
        }
        __syncthreads();

        // ---- phase B: similarity popcounts; lane = v ----
        int pc = 0;
        #pragma unroll 8
        for (int w = 0; w < NW; ++w) {
            const u64 ne = s_X[w] ^ s_est[cur][j][w];
            pc += (int)__popcll(ne ^ cbBj[(w << 6) | lane]);
        }
        const int sim = ND - (pc << 1);
        int msim = sim, spc = pc;
        #pragma unroll
        for (int off = 32; off > 0; off >>= 1) {
            const int t1 = __shfl_xor(msim, off);
            msim = msim > t1 ? msim : t1;
            spc += __shfl_xor(spc, off);
        }
        // bit-planes of pc over v (pc in [0,2048] -> 12 bits)
        u64 c[12];
        #pragma unroll
        for (int k = 0; k < 12; ++k) c[k] = __ballot((pc >> k) & 1);

        // ---- phase C: t_d sign for all d; lane = d%64 ----
        const int tbase = 131072 - (spc << 1);
        int eq1 = 1, eq2 = 1;
        #pragma unroll 4
        for (int k2 = 0; k2 < NW; ++k2) {
            const u64 col = cbTj[(k2 << 6) | lane];
            int t = tbase - ((int)__popcll(col) << 12);
            #pragma unroll
            for (int k = 0; k < 12; ++k)
                t += (int)__popcll(c[k] & col) << (k + 2);
            const u64 nww = __ballot(t < 0);
            eq1 &= (nww == s_est[cur][j][k2]);
            eq2 &= (nww == s_est[pv2][j][k2]);
            if (lane == 0) s_est[nxt][j][k2] = nww;
        }
        if (lane == 0) s_conv[j] = eq1 | (eq2 << 1);
        __syncthreads();

        const int fl = s_conv[0] & s_conv[1] & s_conv[2] & s_conv[3];
        final_slot = nxt;
        m_last = (float)msim;
        if (fl & 1) break;                     // fixed point: all future steps identical
        if (it >= 1 && (fl & 2)) {             // period-2 orbit: resolve by parity
            if (((ITERS - it) & 1) == 0) { final_slot = cur; m_last = (float)m_prev; }
            break;
        }
        m_prev = msim;
    }
    __syncthreads();

    // ---- outcome: argmax_v |sim(est_final, cb)|, first-max tie-break ----
    int pcF = 0;
    #pragma unroll 8
    for (int w = 0; w < NW; ++w)
        pcF += (int)__popcll(s_est[final_slot][j][w] ^ cbBj[(w << 6) | lane]);
    const int simF = ND - (pcF << 1);
    const int aF   = simF < 0 ? -simF : simF;
    int key = (aF << 6) | (63 - lane);
    #pragma unroll
    for (int off = 32; off > 0; off >>= 1) {
        const int t1 = __shfl_xor(key, off);
        key = key > t1 ? key : t1;
    }
    const int vstar = 63 - (key & 63);
    if (lane == 0) {
        out[OFF_OUT + (b << 2) + j] = (float)vstar;
        out[OFF_MS  + (b << 2) + j] = m_last;
    }
    // ---- unpack final estimates ----
    for (int idx = tid; idx < NF * ND; idx += 256) {
        const int jj = idx >> 11, d = idx & 2047;
        const u64 wrd = s_est[final_slot][jj][d >> 6];
        out[(b << 13) + idx] = ((wrd >> (d & 63)) & 1) ? -1.0f : 1.0f;
    }
    if (b == 0 && tid == 0) out[OFF_CONV] = 99.0f;
}

extern "C" void kernel_launch(void* const* d_in, const int* in_sizes, int n_in,
                              void* d_out, int out_size, void* d_ws, size_t ws_size,
                              hipStream_t stream) {
    const float* inp  = (const float*)d_in[0];
    const float* est0 = (const float*)d_in[1];
    const float* cb   = (const float*)d_in[2];
    float* out = (float*)d_out;
    u64* cbB = (u64*)d_ws;                 // 8192 words
    u64* cbT = cbB + NF * NV * NW;         // 8192 words (total 128 KB of ws)

    pack_cb_kernel<<<64, 256, 0, stream>>>(cb, cbB, cbT);
    resonator_kernel<<<NB, 256, 0, stream>>>(inp, est0, cbB, cbT, out);
}